// Round 1
// baseline (3966.491 us; speedup 1.0000x reference)
//
#include <hip/hip_runtime.h>
#include <math.h>

#define S   30
#define FD  200
#define TT  1024
#define BB  1024
#define NC  7

// ---- workspace layout (float offsets) ----
// G_h overlays F2+xs regions (both dead before k_gh runs).
#define OFS_F2   0ull
#define OFS_XS   6144000ull
#define OFS_X1   12288000ull
#define OFS_X2   18432000ull
#define OFS_X3   24576000ull
#define OFS_AF   30720000ull
#define OFS_GV   31641600ull
#define OFS_GH   0ull
#define OFS_G    40857600ull
#define OFS_WCH  40949760ull
#define OFS_WFT  40980480ull
// total floats needed: 41,287,680  (~165.2 MB)

// Generic small GEMM: out[i][j] = (relu?)( sum_k L[i*K+k] * W[k*N+j] ), i<30, j<N.
// Thread t<30*TPI owns row i=t/TPI and columns j = (t%TPI) + m*TPI.
template<int N, int K, int TPI, bool RELU>
__device__ inline void gemm30(const float* L, const float* W, float* out, int ostride) {
    constexpr int M = N / TPI;
    int t = threadIdx.x;
    if (t < S * TPI) {
        int i = t / TPI, sub = t % TPI;
        float acc[M];
#pragma unroll
        for (int m = 0; m < M; m++) acc[m] = 0.f;
        for (int k = 0; k < K; k++) {
            float a = L[i * K + k];
            const float* Wr = W + k * N + sub;
#pragma unroll
            for (int m = 0; m < M; m++) acc[m] += a * Wr[m * TPI];
        }
#pragma unroll
        for (int m = 0; m < M; m++) {
            float v = acc[m];
            if (RELU) v = fmaxf(v, 0.f);
            out[i * ostride + sub + m * TPI] = v;
        }
    }
}

// K1: fused conv1+relu -> conv2+relu -> F2 = relu(h2 @ Wt + bt), per batch b.
// Chunked over T (8 chunks of 128); F2 accumulated in registers.
__global__ __launch_bounds__(256) void k_conv_f2(
    const float* __restrict__ x, const float* __restrict__ Wc1, const float* __restrict__ bc1,
    const float* __restrict__ Wc2, const float* __restrict__ bc2,
    const float* __restrict__ Wt, const float* __restrict__ bt,
    float* __restrict__ F2) {
    const int b = blockIdx.x;
    const int t = threadIdx.x;
    __shared__ float xb[S * 132];   // x tile with halo 2; reused for h2 chunk [S*128]
    __shared__ float h1[S * 130];   // conv1 output with halo 1
    float acc[25];
#pragma unroll
    for (int m = 0; m < 25; m++) acc[m] = 0.f;
    const int i_ = t / 8, sub = t % 8;  // gemm mapping (t<240)

    for (int c = 0; c < 8; c++) {
        const int t0 = c * 128;
        // load x chunk with halo 2 (zero padded at sequence edges)
        for (int idx = t; idx < S * 132; idx += 256) {
            int s = idx / 132, cc = idx % 132;
            int gt = t0 - 2 + cc;
            xb[idx] = (gt >= 0 && gt < TT) ? x[(b * S + s) * TT + gt] : 0.f;
        }
        __syncthreads();
        // conv1 + relu -> h1 (cols map to global t = t0-1+c2); OOB conv1 outputs are 0
        for (int idx = t; idx < S * 130; idx += 256) {
            int s = idx / 130, c2 = idx % 130;
            int gt = t0 - 1 + c2;
            float a = 0.f;
            if (gt >= 0 && gt < TT) {
                a = bc1[s];
                const float* w = Wc1 + s * S * 3;
                for (int si = 0; si < S; si++) {
                    a += w[si * 3 + 0] * xb[si * 132 + c2]
                       + w[si * 3 + 1] * xb[si * 132 + c2 + 1]
                       + w[si * 3 + 2] * xb[si * 132 + c2 + 2];
                }
                a = fmaxf(a, 0.f);
            }
            h1[idx] = a;
        }
        __syncthreads();
        // conv2 + relu -> h2 chunk, stored over xb
        for (int idx = t; idx < S * 128; idx += 256) {
            int s = idx / 128, c3 = idx % 128;
            float a = bc2[s];
            const float* w = Wc2 + s * S * 3;
            for (int si = 0; si < S; si++) {
                a += w[si * 3 + 0] * h1[si * 130 + c3]
                   + w[si * 3 + 1] * h1[si * 130 + c3 + 1]
                   + w[si * 3 + 2] * h1[si * 130 + c3 + 2];
            }
            xb[s * 128 + c3] = fmaxf(a, 0.f);
        }
        __syncthreads();
        // F2 partial: acc += h2chunk @ Wt[t0:t0+128, :]
        if (t < 240) {
            for (int kk = 0; kk < 128; kk++) {
                float a = xb[i_ * 128 + kk];
                const float* Wr = Wt + (t0 + kk) * FD + sub;
#pragma unroll
                for (int m = 0; m < 25; m++) acc[m] += a * Wr[m * 8];
            }
        }
        __syncthreads();
    }
    if (t < 240) {
#pragma unroll
        for (int m = 0; m < 25; m++) {
            int j = sub + m * 8;
            F2[(b * S + i_) * FD + j] = fmaxf(acc[m] + bt[j], 0.f);
        }
    }
}

// K2: A_F = softmax(relu((F2 @ Wa) @ F2^T), axis=-1)
__global__ __launch_bounds__(256) void k_af(const float* __restrict__ F2,
                                            const float* __restrict__ Wa,
                                            float* __restrict__ A_F) {
    int b = blockIdx.x, t = threadIdx.x;
    __shared__ float F2b[S * FD];
    __shared__ float tmp[S * FD];
    __shared__ float sc[S * S];
    for (int idx = t; idx < S * FD; idx += 256) F2b[idx] = F2[b * S * FD + idx];
    __syncthreads();
    gemm30<FD, FD, 8, false>(F2b, Wa, tmp, FD);
    __syncthreads();
    for (int idx = t; idx < S * S; idx += 256) {
        int i = idx / S, j = idx % S;
        float a = 0.f;
        for (int f = 0; f < FD; f++) a += tmp[i * FD + f] * F2b[j * FD + f];
        sc[idx] = fmaxf(a, 0.f);
    }
    __syncthreads();
    if (t < S) {
        float mx = -1e30f;
        for (int j = 0; j < S; j++) mx = fmaxf(mx, sc[t * S + j]);
        float den = 0.f;
        for (int j = 0; j < S; j++) den += expf(sc[t * S + j] - mx);
        float inv = 1.f / den;
        for (int j = 0; j < S; j++) A_F[(b * S + t) * S + j] = expf(sc[t * S + j] - mx) * inv;
    }
}

// K3: one GCN step: Xout = relu((A_F @ Xin) @ Wm)
__global__ __launch_bounds__(256) void k_gc(const float* __restrict__ Xin,
                                            const float* __restrict__ A_F,
                                            const float* __restrict__ Wm,
                                            float* __restrict__ Xout) {
    int b = blockIdx.x, t = threadIdx.x;
    __shared__ float Xb[S * FD];
    __shared__ float Ab[S * S];
    __shared__ float Tb[S * FD];
    for (int idx = t; idx < S * FD; idx += 256) Xb[idx] = Xin[b * S * FD + idx];
    for (int idx = t; idx < S * S; idx += 256) Ab[idx] = A_F[b * S * S + idx];
    __syncthreads();
    gemm30<FD, S, 8, false>(Ab, Xb, Tb, FD);
    __syncthreads();
    gemm30<FD, FD, 8, true>(Tb, Wm, Xout + (size_t)b * S * FD, FD);
}

// K4: x_sensor = adj @ relu((adj @ F2) @ Wg1) @ Wg2   (no final relu)
__global__ __launch_bounds__(256) void k_xs(const float* __restrict__ F2,
                                            const float* __restrict__ adj,
                                            const float* __restrict__ Wg1,
                                            const float* __restrict__ Wg2,
                                            float* __restrict__ xs) {
    int b = blockIdx.x, t = threadIdx.x;
    __shared__ float bufA[S * FD];
    __shared__ float bufB[S * FD];
    __shared__ float adjb[S * S];
    for (int idx = t; idx < S * FD; idx += 256) bufA[idx] = F2[b * S * FD + idx];
    for (int idx = t; idx < S * S; idx += 256) adjb[idx] = adj[idx];
    __syncthreads();
    gemm30<FD, S, 8, false>(adjb, bufA, bufB, FD);      // P = adj@F2
    __syncthreads();
    gemm30<FD, FD, 8, true>(bufB, Wg1, bufA, FD);       // h1 = relu(P@Wg1)
    __syncthreads();
    gemm30<FD, S, 8, false>(adjb, bufA, bufB, FD);      // q = adj@h1
    __syncthreads();
    gemm30<FD, FD, 8, false>(bufB, Wg2, xs + (size_t)b * S * FD, FD);
}

// K5: H_k = 0.5*(x_k + xs) in-place; gate g = softmax_k(H_k . wg[:,k])
__global__ __launch_bounds__(256) void k_hg(float* __restrict__ x1, float* __restrict__ x2,
                                            float* __restrict__ x3, const float* __restrict__ xs,
                                            const float* __restrict__ wg, float* __restrict__ g) {
    int b = blockIdx.x, t = threadIdx.x;
    __shared__ float hb[S * FD];
    __shared__ float sk[S * 3];
    float* xk[3] = {x1, x2, x3};
    for (int k = 0; k < 3; k++) {
        float* xp = xk[k] + (size_t)b * S * FD;
        const float* xsp = xs + (size_t)b * S * FD;
        for (int idx = t; idx < S * FD; idx += 256) {
            float h = 0.5f * (xp[idx] + xsp[idx]);
            xp[idx] = h;
            hb[idx] = h;
        }
        __syncthreads();
        if (t < S) {
            float a = 0.f;
            for (int f = 0; f < FD; f++) a += hb[t * FD + f] * wg[f * 3 + k];
            sk[t * 3 + k] = a;
        }
        __syncthreads();
    }
    if (t < S) {
        float m = fmaxf(sk[t * 3], fmaxf(sk[t * 3 + 1], sk[t * 3 + 2]));
        float e0 = expf(sk[t * 3 + 0] - m);
        float e1 = expf(sk[t * 3 + 1] - m);
        float e2 = expf(sk[t * 3 + 2] - m);
        float inv = 1.f / (e0 + e1 + e2);
        g[(b * S + t) * 3 + 0] = e0 * inv;
        g[(b * S + t) * 3 + 1] = e1 * inv;
        g[(b * S + t) * 3 + 2] = e2 * inv;
    }
}

// K6: G_v = [ relu((adj@F2)@Wl) | relu((A_F@F2)@Wgl) ]
__global__ __launch_bounds__(256) void k_gv(const float* __restrict__ F2, const float* __restrict__ A_F,
                                            const float* __restrict__ adj, const float* __restrict__ Wl,
                                            const float* __restrict__ Wgl, float* __restrict__ Gv) {
    int b = blockIdx.x, t = threadIdx.x;
    __shared__ float F2b[S * FD];
    __shared__ float Ab[S * S];
    __shared__ float adjb[S * S];
    __shared__ float Tb[S * FD];
    for (int idx = t; idx < S * FD; idx += 256) F2b[idx] = F2[b * S * FD + idx];
    for (int idx = t; idx < S * S; idx += 256) { Ab[idx] = A_F[b * S * S + idx]; adjb[idx] = adj[idx]; }
    __syncthreads();
    gemm30<FD, S, 8, false>(adjb, F2b, Tb, FD);                    // P
    __syncthreads();
    gemm30<150, FD, 5, true>(Tb, Wl, Gv + (size_t)b * S * 300, 300);        // loc
    __syncthreads();
    gemm30<FD, S, 8, false>(Ab, F2b, Tb, FD);                      // T1
    __syncthreads();
    gemm30<150, FD, 5, true>(Tb, Wgl, Gv + (size_t)b * S * 300 + 150, 300); // glb
}

// K7: G_h[:, k*100:(k+1)*100] = (adj * g_k-cols) @ H_k @ Wp_k   (no relu)
__global__ __launch_bounds__(256) void k_gh(const float* __restrict__ x1, const float* __restrict__ x2,
                                            const float* __restrict__ x3, const float* __restrict__ g,
                                            const float* __restrict__ adj,
                                            const float* __restrict__ Wp1, const float* __restrict__ Wp2,
                                            const float* __restrict__ Wp3, float* __restrict__ Gh) {
    int b = blockIdx.x, t = threadIdx.x;
    __shared__ float Hb[S * FD];
    __shared__ float Tb[S * FD];
    __shared__ float As[S * S];
    const float* xk[3] = {x1, x2, x3};
    const float* Wp[3] = {Wp1, Wp2, Wp3};
    for (int k = 0; k < 3; k++) {
        for (int idx = t; idx < S * FD; idx += 256) Hb[idx] = xk[k][(size_t)b * S * FD + idx];
        for (int idx = t; idx < S * S; idx += 256) {
            int j = idx % S;
            As[idx] = adj[idx] * g[(b * S + j) * 3 + k];
        }
        __syncthreads();
        gemm30<FD, S, 8, false>(As, Hb, Tb, FD);
        __syncthreads();
        gemm30<100, FD, 4, false>(Tb, Wp[k], Gh + (size_t)b * S * 300 + k * 100, 300);
        __syncthreads();
    }
}

// K8: squeeze-excitation gates wch [B,S] and wft [B,300]
__global__ __launch_bounds__(256) void k_se(const float* __restrict__ Gv, const float* __restrict__ Gh,
                                            const float* __restrict__ Ws1, const float* __restrict__ Ws2,
                                            const float* __restrict__ Wf1, const float* __restrict__ Wf2,
                                            float* __restrict__ wch, float* __restrict__ wft) {
    int b = blockIdx.x, t = threadIdx.x;
    __shared__ float mrow[S];
    __shared__ float u[15];
    __shared__ float mb[300];
    __shared__ float v[150];
    if (t < S) {
        float a = 0.f;
        const float* gp = Gv + ((size_t)b * S + t) * 300;
        for (int j = 0; j < 300; j++) a += gp[j];
        mrow[t] = a * (1.f / 300.f);
    }
    for (int j = t; j < 300; j += 256) {
        float a = 0.f;
        for (int s = 0; s < S; s++) a += Gh[(size_t)b * S * 300 + s * 300 + j];
        mb[j] = a * (1.f / S);
    }
    __syncthreads();
    if (t < 15) {
        float a = 0.f;
        for (int i = 0; i < S; i++) a += mrow[i] * Ws1[i * 15 + t];
        u[t] = fmaxf(a, 0.f);
    }
    if (t >= 64 && t < 64 + 150) {
        int h = t - 64;
        float a = 0.f;
        for (int j = 0; j < 300; j++) a += mb[j] * Wf1[j * 150 + h];
        v[h] = fmaxf(a, 0.f);
    }
    __syncthreads();
    if (t < S) {
        float a = 0.f;
        for (int h = 0; h < 15; h++) a += u[h] * Ws2[h * 30 + t];
        wch[b * S + t] = 1.f / (1.f + expf(-a));
    }
    for (int j = t; j < 300; j += 256) {
        float a = 0.f;
        for (int h = 0; h < 150; h++) a += v[h] * Wf2[h * 300 + j];
        wft[b * 300 + j] = 1.f / (1.f + expf(-a));
    }
}

// K9: logits = [G_h*wch | G_v*wft].flatten() @ Wcls + bcls ; out = log_softmax
__global__ __launch_bounds__(256) void k_cls(const float* __restrict__ Gh, const float* __restrict__ Gv,
                                             const float* __restrict__ wch, const float* __restrict__ wft,
                                             const float* __restrict__ Wcls, const float* __restrict__ bcls,
                                             float* __restrict__ out) {
    int b = blockIdx.x, t = threadIdx.x;
    __shared__ float red[NC][256];
    float acc[NC];
#pragma unroll
    for (int c = 0; c < NC; c++) acc[c] = 0.f;
    for (int i = t; i < S * 600; i += 256) {
        int s = i / 600, j = i % 600;
        float gval = (j < 300)
            ? Gh[(size_t)b * S * 300 + s * 300 + j] * wch[b * S + s]
            : Gv[(size_t)b * S * 300 + s * 300 + (j - 300)] * wft[b * 300 + (j - 300)];
        const float* wr = Wcls + (size_t)i * NC;
#pragma unroll
        for (int c = 0; c < NC; c++) acc[c] += gval * wr[c];
    }
#pragma unroll
    for (int c = 0; c < NC; c++) red[c][t] = acc[c];
    __syncthreads();
    for (int off = 128; off > 0; off >>= 1) {
        if (t < off) {
#pragma unroll
            for (int c = 0; c < NC; c++) red[c][t] += red[c][t + off];
        }
        __syncthreads();
    }
    if (t == 0) {
        float lg[NC];
        float mx = -1e30f;
#pragma unroll
        for (int c = 0; c < NC; c++) { lg[c] = red[c][0] + bcls[c]; mx = fmaxf(mx, lg[c]); }
        float den = 0.f;
#pragma unroll
        for (int c = 0; c < NC; c++) den += expf(lg[c] - mx);
        float lden = logf(den) + mx;
#pragma unroll
        for (int c = 0; c < NC; c++) out[b * NC + c] = lg[c] - lden;
    }
}

extern "C" void kernel_launch(void* const* d_in, const int* in_sizes, int n_in,
                              void* d_out, int out_size, void* d_ws, size_t ws_size,
                              hipStream_t stream) {
    const float* x    = (const float*)d_in[0];
    const float* adj  = (const float*)d_in[1];
    const float* Wc1  = (const float*)d_in[2];
    const float* bc1  = (const float*)d_in[3];
    const float* Wc2  = (const float*)d_in[4];
    const float* bc2  = (const float*)d_in[5];
    const float* Wt   = (const float*)d_in[6];
    const float* bt   = (const float*)d_in[7];
    const float* Wa   = (const float*)d_in[8];
    const float* Wm1  = (const float*)d_in[9];
    const float* Wm2  = (const float*)d_in[10];
    const float* Wm3  = (const float*)d_in[11];
    const float* Wg1  = (const float*)d_in[12];
    const float* Wg2  = (const float*)d_in[13];
    const float* wg   = (const float*)d_in[14];
    const float* Wp1  = (const float*)d_in[15];
    const float* Wp2  = (const float*)d_in[16];
    const float* Wp3  = (const float*)d_in[17];
    const float* Wl   = (const float*)d_in[18];
    const float* Wgl  = (const float*)d_in[19];
    const float* Ws1  = (const float*)d_in[20];
    const float* Ws2  = (const float*)d_in[21];
    const float* Wf1  = (const float*)d_in[22];
    const float* Wf2  = (const float*)d_in[23];
    const float* Wcls = (const float*)d_in[24];
    const float* bcls = (const float*)d_in[25];

    float* ws  = (float*)d_ws;
    float* F2  = ws + OFS_F2;
    float* XS  = ws + OFS_XS;
    float* X1  = ws + OFS_X1;
    float* X2  = ws + OFS_X2;
    float* X3  = ws + OFS_X3;
    float* AF  = ws + OFS_AF;
    float* GV  = ws + OFS_GV;
    float* GH  = ws + OFS_GH;   // overlays F2/XS (dead by then)
    float* Gg  = ws + OFS_G;
    float* WCH = ws + OFS_WCH;
    float* WFT = ws + OFS_WFT;
    float* out = (float*)d_out;

    dim3 grid(BB), blk(256);
    k_conv_f2<<<grid, blk, 0, stream>>>(x, Wc1, bc1, Wc2, bc2, Wt, bt, F2);
    k_af<<<grid, blk, 0, stream>>>(F2, Wa, AF);
    k_gc<<<grid, blk, 0, stream>>>(F2, AF, Wm1, X1);
    k_gc<<<grid, blk, 0, stream>>>(X1, AF, Wm2, X2);
    k_gc<<<grid, blk, 0, stream>>>(X2, AF, Wm3, X3);
    k_xs<<<grid, blk, 0, stream>>>(F2, adj, Wg1, Wg2, XS);
    k_hg<<<grid, blk, 0, stream>>>(X1, X2, X3, XS, wg, Gg);
    k_gv<<<grid, blk, 0, stream>>>(F2, AF, adj, Wl, Wgl, GV);   // last reader of F2
    k_gh<<<grid, blk, 0, stream>>>(X1, X2, X3, Gg, adj, Wp1, Wp2, Wp3, GH); // overwrites F2/XS region
    k_se<<<grid, blk, 0, stream>>>(GV, GH, Ws1, Ws2, Wf1, Wf2, WCH, WFT);
    k_cls<<<grid, blk, 0, stream>>>(GH, GV, WCH, WFT, Wcls, bcls, out);
}

// Round 2
// 1892.730 us; speedup vs baseline: 2.0956x; 2.0956x over previous
//
#include <hip/hip_runtime.h>
#include <math.h>

#define S   30
#define FD  200
#define TT  1024
#define BB  1024
#define NC  7

// ---- workspace layout (float offsets), overlaid by live range ----
// h2 [0, 31457280) lives only conv->f2. After that its region is reused:
//   X1@0, X2@6.144M, X3@12.288M, XS@18.432M (dead after k_hg),
//   GH@18.432M..27.648M (written k_gh, after XS dead),
//   AF@27.648M, g@28.5696M, wch@28.66176M, wft@28.69248M,
//   GV@0 (written k_loc/k_glb AFTER k_gh has consumed X1..X3).
// F2 lives outside at 31.45728M. Total 37,601,280 floats = 150.4 MB.
#define OFS_H2   0ull
#define OFS_X1   0ull
#define OFS_X2   6144000ull
#define OFS_X3   12288000ull
#define OFS_XS   18432000ull
#define OFS_GH   18432000ull
#define OFS_AF   27648000ull
#define OFS_G    28569600ull
#define OFS_WCH  28661760ull
#define OFS_WFT  28692480ull
#define OFS_GV   0ull
#define OFS_F2   31457280ull

// ---------------- K1: conv1+relu -> conv2+relu -> h2 ----------------
// Grid (8, B), 128 threads. Per thread: 3 x-values live, acc[30] outputs,
// weights via wave-uniform addresses -> scalar loads (co-issued on SALU pipe).
__global__ __launch_bounds__(128) void k_conv(
    const float* __restrict__ x,
    const float* __restrict__ Wc1, const float* __restrict__ bc1,
    const float* __restrict__ Wc2, const float* __restrict__ bc2,
    float* __restrict__ h2) {
    const int c = blockIdx.x, b = blockIdx.y;
    const int tid = threadIdx.x;
    const int t0 = c * 128;
    __shared__ float xb[S * 132];   // x tile, halo 2 each side: gt = t0-2+j
    __shared__ float h1[S * 132];   // conv1 out, pos i <-> gt = t0-1+i, i<130
    for (int idx = tid; idx < S * 132; idx += 128) {
        int s = idx / 132, j = idx % 132;
        int gt = t0 - 2 + j;
        xb[idx] = (gt >= 0 && gt < TT) ? x[(b * S + s) * TT + gt] : 0.f;
    }
    __syncthreads();
    for (int i = tid; i < 130; i += 128) {
        int gt = t0 - 1 + i;
        float acc[S];
#pragma unroll
        for (int so = 0; so < S; so++) acc[so] = bc1[so];
        for (int si = 0; si < S; si++) {
            float v0 = xb[si * 132 + i], v1 = xb[si * 132 + i + 1], v2 = xb[si * 132 + i + 2];
            const float* w = Wc1 + si * 3;
#pragma unroll
            for (int so = 0; so < S; so++) {
                acc[so] = fmaf(w[so * 90 + 0], v0, acc[so]);
                acc[so] = fmaf(w[so * 90 + 1], v1, acc[so]);
                acc[so] = fmaf(w[so * 90 + 2], v2, acc[so]);
            }
        }
        bool ok = (gt >= 0 && gt < TT);
#pragma unroll
        for (int so = 0; so < S; so++)
            h1[so * 132 + i] = ok ? fmaxf(acc[so], 0.f) : 0.f;
    }
    __syncthreads();
    {
        int i = tid;  // global t = t0+tid; h1 tile idx of t-1 is tid
        float acc[S];
#pragma unroll
        for (int so = 0; so < S; so++) acc[so] = bc2[so];
        for (int si = 0; si < S; si++) {
            float v0 = h1[si * 132 + i], v1 = h1[si * 132 + i + 1], v2 = h1[si * 132 + i + 2];
            const float* w = Wc2 + si * 3;
#pragma unroll
            for (int so = 0; so < S; so++) {
                acc[so] = fmaf(w[so * 90 + 0], v0, acc[so]);
                acc[so] = fmaf(w[so * 90 + 1], v1, acc[so]);
                acc[so] = fmaf(w[so * 90 + 2], v2, acc[so]);
            }
        }
#pragma unroll
        for (int so = 0; so < S; so++)
            h2[(b * S + so) * TT + t0 + tid] = fmaxf(acc[so], 0.f);
    }
}

// ---------------- K2: F2 = relu(h2 @ Wt + bt) ----------------
// Per-b block, 250 active threads: ct=t%50 (4 cols), rt=t/50 (6 rows).
__global__ __launch_bounds__(256) void k_f2(
    const float* __restrict__ h2, const float* __restrict__ Wt,
    const float* __restrict__ bt, float* __restrict__ F2) {
    const int b = blockIdx.x, t = threadIdx.x;
    __shared__ float xsl[S * 64];
    const int ct = t % 50, rt = t / 50;
    float acc[6][4];
#pragma unroll
    for (int m = 0; m < 6; m++)
#pragma unroll
        for (int q = 0; q < 4; q++) acc[m][q] = 0.f;
    for (int ks = 0; ks < 16; ks++) {
        for (int idx = t; idx < S * 64; idx += 256) {
            int s = idx / 64, kk = idx % 64;
            xsl[idx] = h2[(b * S + s) * TT + ks * 64 + kk];
        }
        __syncthreads();
        if (t < 250) {
#pragma unroll 4
            for (int kk = 0; kk < 64; kk++) {
                const float4 w = *(const float4*)(Wt + (ks * 64 + kk) * FD + 4 * ct);
#pragma unroll
                for (int m = 0; m < 6; m++) {
                    float a = xsl[(rt * 6 + m) * 64 + kk];
                    acc[m][0] = fmaf(a, w.x, acc[m][0]);
                    acc[m][1] = fmaf(a, w.y, acc[m][1]);
                    acc[m][2] = fmaf(a, w.z, acc[m][2]);
                    acc[m][3] = fmaf(a, w.w, acc[m][3]);
                }
            }
        }
        __syncthreads();
    }
    if (t < 250) {
#pragma unroll
        for (int m = 0; m < 6; m++) {
            int row = rt * 6 + m;
            float4 o;
            o.x = fmaxf(acc[m][0] + bt[4 * ct + 0], 0.f);
            o.y = fmaxf(acc[m][1] + bt[4 * ct + 1], 0.f);
            o.z = fmaxf(acc[m][2] + bt[4 * ct + 2], 0.f);
            o.w = fmaxf(acc[m][3] + bt[4 * ct + 3], 0.f);
            *(float4*)(F2 + (size_t)(b * S + row) * FD + 4 * ct) = o;
        }
    }
}

// ------------- shared GEMM helpers (per-b 30-row tiles) -------------
// acc[m][q] += sum_k Xl[(rt*RPT+m)*xstr + k] * W[k*N + 4ct + q], W global float4
template<int RPT>
__device__ inline void gemm_w4(const float* Xl, int xstr, const float* __restrict__ W,
                               int N, int K, int ct, int rt, float acc[][4]) {
#pragma unroll 2
    for (int k = 0; k < K; k++) {
        const float4 w = *(const float4*)(W + k * N + 4 * ct);
#pragma unroll
        for (int m = 0; m < RPT; m++) {
            float a = Xl[(rt * RPT + m) * xstr + k];
            acc[m][0] = fmaf(a, w.x, acc[m][0]);
            acc[m][1] = fmaf(a, w.y, acc[m][1]);
            acc[m][2] = fmaf(a, w.z, acc[m][2]);
            acc[m][3] = fmaf(a, w.w, acc[m][3]);
        }
    }
}

// acc[m][q] += sum_k Al[(rt*RPT+m)*S + k] * Xl[k*xstr + 4ct + q]  (K = S = 30)
template<int RPT>
__device__ inline void gemm_a(const float* Al, const float* Xl, int xstr,
                              int ct, int rt, float acc[][4]) {
#pragma unroll 2
    for (int k = 0; k < S; k++) {
        const float4 xv = *(const float4*)(Xl + k * xstr + 4 * ct);
#pragma unroll
        for (int m = 0; m < RPT; m++) {
            float a = Al[(rt * RPT + m) * S + k];
            acc[m][0] = fmaf(a, xv.x, acc[m][0]);
            acc[m][1] = fmaf(a, xv.y, acc[m][1]);
            acc[m][2] = fmaf(a, xv.z, acc[m][2]);
            acc[m][3] = fmaf(a, xv.w, acc[m][3]);
        }
    }
}

template<int RPT>
__device__ inline void zacc(float acc[][4]) {
#pragma unroll
    for (int m = 0; m < RPT; m++)
#pragma unroll
        for (int q = 0; q < 4; q++) acc[m][q] = 0.f;
}

// ---------------- K3: A_F = softmax(relu((F2@Wa)@F2^T)) ----------------
__global__ __launch_bounds__(256) void k_af(const float* __restrict__ F2,
                                            const float* __restrict__ Wa,
                                            float* __restrict__ AF) {
    const int b = blockIdx.x, t = threadIdx.x;
    __shared__ float F2b[S * 201];  // stride 201: kills stride-200 bank aliasing in scores
    __shared__ float P[S * 201];
    __shared__ float sc[S * S];
    for (int idx = t; idx < S * FD; idx += 256) {
        int r = idx / FD, cc = idx % FD;
        F2b[r * 201 + cc] = F2[(size_t)b * S * FD + idx];
    }
    __syncthreads();
    const int ct = t % 50, rt = t / 50;
    float acc[6][4];
    zacc<6>(acc);
    if (t < 250) gemm_w4<6>(F2b, 201, Wa, FD, FD, ct, rt, acc);
    if (t < 250) {
#pragma unroll
        for (int m = 0; m < 6; m++)
#pragma unroll
            for (int q = 0; q < 4; q++) P[(rt * 6 + m) * 201 + 4 * ct + q] = acc[m][q];
    }
    __syncthreads();
    for (int idx = t; idx < S * S; idx += 256) {
        int i = idx / S, j = idx % S;
        float a = 0.f;
        for (int f = 0; f < FD; f++) a = fmaf(P[i * 201 + f], F2b[j * 201 + f], a);
        sc[idx] = fmaxf(a, 0.f);
    }
    __syncthreads();
    if (t < S) {
        float mx = -1e30f;
        for (int j = 0; j < S; j++) mx = fmaxf(mx, sc[t * S + j]);
        float den = 0.f;
        for (int j = 0; j < S; j++) den += expf(sc[t * S + j] - mx);
        float inv = 1.f / den;
        for (int j = 0; j < S; j++) AF[(size_t)(b * S + t) * S + j] = expf(sc[t * S + j] - mx) * inv;
    }
}

// ---------------- K4: Xout = relu((A@Xin)@Wm) ----------------
__global__ __launch_bounds__(256) void k_gc(const float* __restrict__ Xin,
                                            const float* __restrict__ AF,
                                            const float* __restrict__ Wm,
                                            float* __restrict__ Xout) {
    const int b = blockIdx.x, t = threadIdx.x;
    __shared__ float Xl[S * FD];
    __shared__ float Al[S * S];
    for (int idx = t; idx < S * FD; idx += 256) Xl[idx] = Xin[(size_t)b * S * FD + idx];
    for (int idx = t; idx < S * S; idx += 256) Al[idx] = AF[(size_t)b * S * S + idx];
    __syncthreads();
    const int ct = t % 50, rt = t / 50;
    float acc[6][4];
    zacc<6>(acc);
    if (t < 250) gemm_a<6>(Al, Xl, FD, ct, rt, acc);
    __syncthreads();
    if (t < 250) {
#pragma unroll
        for (int m = 0; m < 6; m++) {
            float4 o = {acc[m][0], acc[m][1], acc[m][2], acc[m][3]};
            *(float4*)(Xl + (rt * 6 + m) * FD + 4 * ct) = o;
        }
    }
    __syncthreads();
    zacc<6>(acc);
    if (t < 250) {
        gemm_w4<6>(Xl, FD, Wm, FD, FD, ct, rt, acc);
#pragma unroll
        for (int m = 0; m < 6; m++) {
            float4 o;
            o.x = fmaxf(acc[m][0], 0.f); o.y = fmaxf(acc[m][1], 0.f);
            o.z = fmaxf(acc[m][2], 0.f); o.w = fmaxf(acc[m][3], 0.f);
            *(float4*)(Xout + (size_t)(b * S + rt * 6 + m) * FD + 4 * ct) = o;
        }
    }
}

// ---------------- K5: x_sensor = adj@relu((adj@F2)@Wg1)@Wg2 ----------------
__global__ __launch_bounds__(256) void k_xs(const float* __restrict__ F2,
                                            const float* __restrict__ adj,
                                            const float* __restrict__ Wg1,
                                            const float* __restrict__ Wg2,
                                            float* __restrict__ xs) {
    const int b = blockIdx.x, t = threadIdx.x;
    __shared__ float Xl[S * FD];
    __shared__ float Al[S * S];
    for (int idx = t; idx < S * FD; idx += 256) Xl[idx] = F2[(size_t)b * S * FD + idx];
    for (int idx = t; idx < S * S; idx += 256) Al[idx] = adj[idx];
    __syncthreads();
    const int ct = t % 50, rt = t / 50;
    float acc[6][4];
    // P = adj@F2
    zacc<6>(acc);
    if (t < 250) gemm_a<6>(Al, Xl, FD, ct, rt, acc);
    __syncthreads();
    if (t < 250)
#pragma unroll
        for (int m = 0; m < 6; m++) {
            float4 o = {acc[m][0], acc[m][1], acc[m][2], acc[m][3]};
            *(float4*)(Xl + (rt * 6 + m) * FD + 4 * ct) = o;
        }
    __syncthreads();
    // h = relu(P@Wg1)
    zacc<6>(acc);
    if (t < 250) gemm_w4<6>(Xl, FD, Wg1, FD, FD, ct, rt, acc);
    __syncthreads();
    if (t < 250)
#pragma unroll
        for (int m = 0; m < 6; m++) {
            float4 o;
            o.x = fmaxf(acc[m][0], 0.f); o.y = fmaxf(acc[m][1], 0.f);
            o.z = fmaxf(acc[m][2], 0.f); o.w = fmaxf(acc[m][3], 0.f);
            *(float4*)(Xl + (rt * 6 + m) * FD + 4 * ct) = o;
        }
    __syncthreads();
    // q = adj@h
    zacc<6>(acc);
    if (t < 250) gemm_a<6>(Al, Xl, FD, ct, rt, acc);
    __syncthreads();
    if (t < 250)
#pragma unroll
        for (int m = 0; m < 6; m++) {
            float4 o = {acc[m][0], acc[m][1], acc[m][2], acc[m][3]};
            *(float4*)(Xl + (rt * 6 + m) * FD + 4 * ct) = o;
        }
    __syncthreads();
    // xs = q@Wg2 (no relu)
    zacc<6>(acc);
    if (t < 250) {
        gemm_w4<6>(Xl, FD, Wg2, FD, FD, ct, rt, acc);
#pragma unroll
        for (int m = 0; m < 6; m++) {
            float4 o = {acc[m][0], acc[m][1], acc[m][2], acc[m][3]};
            *(float4*)(xs + (size_t)(b * S + rt * 6 + m) * FD + 4 * ct) = o;
        }
    }
}

// ---------------- K6: H_k = 0.5*(x_k+xs) in place; gate g ----------------
__global__ __launch_bounds__(256) void k_hg(float* __restrict__ x1, float* __restrict__ x2,
                                            float* __restrict__ x3, const float* __restrict__ xs,
                                            const float* __restrict__ wg, float* __restrict__ g) {
    int b = blockIdx.x, t = threadIdx.x;
    __shared__ float hb[S * FD];
    __shared__ float sk[S * 3];
    float* xk[3] = {x1, x2, x3};
    for (int k = 0; k < 3; k++) {
        float* xp = xk[k] + (size_t)b * S * FD;
        const float* xsp = xs + (size_t)b * S * FD;
        for (int idx = t; idx < S * FD; idx += 256) {
            float h = 0.5f * (xp[idx] + xsp[idx]);
            xp[idx] = h;
            hb[idx] = h;
        }
        __syncthreads();
        if (t < S) {
            float a = 0.f;
            for (int f = 0; f < FD; f++) a = fmaf(hb[t * FD + f], wg[f * 3 + k], a);
            sk[t * 3 + k] = a;
        }
        __syncthreads();
    }
    if (t < S) {
        float m = fmaxf(sk[t * 3], fmaxf(sk[t * 3 + 1], sk[t * 3 + 2]));
        float e0 = expf(sk[t * 3 + 0] - m);
        float e1 = expf(sk[t * 3 + 1] - m);
        float e2 = expf(sk[t * 3 + 2] - m);
        float inv = 1.f / (e0 + e1 + e2);
        g[(b * S + t) * 3 + 0] = e0 * inv;
        g[(b * S + t) * 3 + 1] = e1 * inv;
        g[(b * S + t) * 3 + 2] = e2 * inv;
    }
}

// ---------------- K7: G_h chunks = (adj*g_k)@H_k@Wp_k ----------------
__global__ __launch_bounds__(256) void k_gh(const float* __restrict__ x1, const float* __restrict__ x2,
                                            const float* __restrict__ x3, const float* __restrict__ g,
                                            const float* __restrict__ adj,
                                            const float* __restrict__ Wp1, const float* __restrict__ Wp2,
                                            const float* __restrict__ Wp3, float* __restrict__ Gh) {
    const int b = blockIdx.x, t = threadIdx.x;
    __shared__ float Xl[S * FD];
    __shared__ float Al[S * S];
    const float* xk[3] = {x1, x2, x3};
    const float* Wp[3] = {Wp1, Wp2, Wp3};
    const int ct = t % 50, rt = t / 50;       // N=200 map
    const int ct3 = t % 25, rt3 = t / 25;     // N=100 map (RPT=3)
    for (int kk = 0; kk < 3; kk++) {
        for (int idx = t; idx < S * FD; idx += 256) Xl[idx] = xk[kk][(size_t)b * S * FD + idx];
        for (int idx = t; idx < S * S; idx += 256) {
            int j = idx % S;
            Al[idx] = adj[idx] * g[(b * S + j) * 3 + kk];
        }
        __syncthreads();
        float acc[6][4];
        zacc<6>(acc);
        if (t < 250) gemm_a<6>(Al, Xl, FD, ct, rt, acc);
        __syncthreads();
        if (t < 250)
#pragma unroll
            for (int m = 0; m < 6; m++) {
                float4 o = {acc[m][0], acc[m][1], acc[m][2], acc[m][3]};
                *(float4*)(Xl + (rt * 6 + m) * FD + 4 * ct) = o;
            }
        __syncthreads();
        float acc3[3][4];
        zacc<3>(acc3);
        if (t < 250) {
            gemm_w4<3>(Xl, FD, Wp[kk], 100, FD, ct3, rt3, acc3);
#pragma unroll
            for (int m = 0; m < 3; m++) {
                float4 o = {acc3[m][0], acc3[m][1], acc3[m][2], acc3[m][3]};
                *(float4*)(Gh + (size_t)(b * S + rt3 * 3 + m) * 300 + kk * 100 + 4 * ct3) = o;
            }
        }
        __syncthreads();
    }
}

// ---------------- K8a/b: G_v halves ----------------
// N=150 map: ct2=t%38 (cols 4ct2, last group only 2), rt2=t/38 (<6, RPT=5), t<228
__device__ inline void gemm_w150(const float* Xl, const float* __restrict__ W,
                                 int ct2, int rt2, float acc[5][4], bool full) {
#pragma unroll 2
    for (int k = 0; k < FD; k++) {
        const float* wr = W + k * 150 + 4 * ct2;
        float2 w01 = *(const float2*)(wr);
        float2 w23 = full ? *(const float2*)(wr + 2) : make_float2(0.f, 0.f);
#pragma unroll
        for (int m = 0; m < 5; m++) {
            float a = Xl[(rt2 * 5 + m) * FD + k];
            acc[m][0] = fmaf(a, w01.x, acc[m][0]);
            acc[m][1] = fmaf(a, w01.y, acc[m][1]);
            acc[m][2] = fmaf(a, w23.x, acc[m][2]);
            acc[m][3] = fmaf(a, w23.y, acc[m][3]);
        }
    }
}

__global__ __launch_bounds__(256) void k_loc(const float* __restrict__ F2,
                                             const float* __restrict__ adj,
                                             const float* __restrict__ Wl,
                                             float* __restrict__ Gv) {
    const int b = blockIdx.x, t = threadIdx.x;
    __shared__ float Xl[S * FD];
    __shared__ float Al[S * S];
    for (int idx = t; idx < S * FD; idx += 256) Xl[idx] = F2[(size_t)b * S * FD + idx];
    for (int idx = t; idx < S * S; idx += 256) Al[idx] = adj[idx];
    __syncthreads();
    const int ct = t % 50, rt = t / 50;
    float acc[6][4];
    zacc<6>(acc);
    if (t < 250) gemm_a<6>(Al, Xl, FD, ct, rt, acc);
    __syncthreads();
    if (t < 250)
#pragma unroll
        for (int m = 0; m < 6; m++) {
            float4 o = {acc[m][0], acc[m][1], acc[m][2], acc[m][3]};
            *(float4*)(Xl + (rt * 6 + m) * FD + 4 * ct) = o;
        }
    __syncthreads();
    const int ct2 = t % 38, rt2 = t / 38;
    if (t < 228) {
        bool full = (4 * ct2 + 2) < 150;
        float a2[5][4];
        zacc<5>(a2);
        gemm_w150(Xl, Wl, ct2, rt2, a2, full);
#pragma unroll
        for (int m = 0; m < 5; m++) {
            int row = rt2 * 5 + m;
            float* o = Gv + (size_t)(b * S + row) * 300 + 4 * ct2;
            o[0] = fmaxf(a2[m][0], 0.f);
            o[1] = fmaxf(a2[m][1], 0.f);
            if (full) { o[2] = fmaxf(a2[m][2], 0.f); o[3] = fmaxf(a2[m][3], 0.f); }
        }
    }
}

__global__ __launch_bounds__(256) void k_glb(const float* __restrict__ F2,
                                             const float* __restrict__ AF,
                                             const float* __restrict__ Wgl,
                                             float* __restrict__ Gv) {
    const int b = blockIdx.x, t = threadIdx.x;
    __shared__ float Xl[S * FD];
    __shared__ float Al[S * S];
    for (int idx = t; idx < S * FD; idx += 256) Xl[idx] = F2[(size_t)b * S * FD + idx];
    for (int idx = t; idx < S * S; idx += 256) Al[idx] = AF[(size_t)b * S * S + idx];
    __syncthreads();
    const int ct = t % 50, rt = t / 50;
    float acc[6][4];
    zacc<6>(acc);
    if (t < 250) gemm_a<6>(Al, Xl, FD, ct, rt, acc);
    __syncthreads();
    if (t < 250)
#pragma unroll
        for (int m = 0; m < 6; m++) {
            float4 o = {acc[m][0], acc[m][1], acc[m][2], acc[m][3]};
            *(float4*)(Xl + (rt * 6 + m) * FD + 4 * ct) = o;
        }
    __syncthreads();
    const int ct2 = t % 38, rt2 = t / 38;
    if (t < 228) {
        bool full = (4 * ct2 + 2) < 150;
        float a2[5][4];
        zacc<5>(a2);
        gemm_w150(Xl, Wgl, ct2, rt2, a2, full);
#pragma unroll
        for (int m = 0; m < 5; m++) {
            int row = rt2 * 5 + m;
            float* o = Gv + (size_t)(b * S + row) * 300 + 150 + 4 * ct2;
            o[0] = fmaxf(a2[m][0], 0.f);
            o[1] = fmaxf(a2[m][1], 0.f);
            if (full) { o[2] = fmaxf(a2[m][2], 0.f); o[3] = fmaxf(a2[m][3], 0.f); }
        }
    }
}

// ---------------- K9: SE gates ----------------
__global__ __launch_bounds__(256) void k_se(const float* __restrict__ Gv, const float* __restrict__ Gh,
                                            const float* __restrict__ Ws1, const float* __restrict__ Ws2,
                                            const float* __restrict__ Wf1, const float* __restrict__ Wf2,
                                            float* __restrict__ wch, float* __restrict__ wft) {
    int b = blockIdx.x, t = threadIdx.x;
    __shared__ float mrow[S];
    __shared__ float u[15];
    __shared__ float mb[300];
    __shared__ float v[150];
    if (t < S) {
        float a = 0.f;
        const float* gp = Gv + ((size_t)b * S + t) * 300;
        for (int j = 0; j < 300; j++) a += gp[j];
        mrow[t] = a * (1.f / 300.f);
    }
    for (int j = t; j < 300; j += 256) {
        float a = 0.f;
        for (int s = 0; s < S; s++) a += Gh[(size_t)b * S * 300 + s * 300 + j];
        mb[j] = a * (1.f / S);
    }
    __syncthreads();
    if (t < 15) {
        float a = 0.f;
        for (int i = 0; i < S; i++) a += mrow[i] * Ws1[i * 15 + t];
        u[t] = fmaxf(a, 0.f);
    }
    if (t >= 64 && t < 64 + 150) {
        int h = t - 64;
        float a = 0.f;
        for (int j = 0; j < 300; j++) a += mb[j] * Wf1[j * 150 + h];
        v[h] = fmaxf(a, 0.f);
    }
    __syncthreads();
    if (t < S) {
        float a = 0.f;
        for (int h = 0; h < 15; h++) a += u[h] * Ws2[h * 30 + t];
        wch[b * S + t] = 1.f / (1.f + expf(-a));
    }
    for (int j = t; j < 300; j += 256) {
        float a = 0.f;
        for (int h = 0; h < 150; h++) a += v[h] * Wf2[h * 300 + j];
        wft[b * 300 + j] = 1.f / (1.f + expf(-a));
    }
}

// ---------------- K10: classifier + log_softmax ----------------
// 8 b's per block; Wcls staged per-s in LDS (cuts Wcls L2 re-reads 8x).
__global__ __launch_bounds__(256) void k_cls(const float* __restrict__ Gh, const float* __restrict__ Gv,
                                             const float* __restrict__ wch, const float* __restrict__ wft,
                                             const float* __restrict__ Wcls, const float* __restrict__ bcls,
                                             float* __restrict__ out) {
    const int bt = threadIdx.x / 32, ln = threadIdx.x % 32;
    const int b = blockIdx.x * 8 + bt;
    __shared__ float wsl[600 * NC];
    __shared__ float wftl[8 * 300];
    for (int idx = threadIdx.x; idx < 8 * 300; idx += 256)
        wftl[idx] = wft[(size_t)blockIdx.x * 8 * 300 + idx];
    float acc[NC];
#pragma unroll
    for (int c = 0; c < NC; c++) acc[c] = 0.f;
    for (int s = 0; s < S; s++) {
        __syncthreads();
        for (int idx = threadIdx.x; idx < 600 * NC; idx += 256)
            wsl[idx] = Wcls[(size_t)s * 600 * NC + idx];
        __syncthreads();
        float wchv = wch[b * S + s];
        const float* ghr = Gh + (size_t)(b * S + s) * 300;
        const float* gvr = Gv + (size_t)(b * S + s) * 300;
        for (int j = ln; j < 600; j += 32) {
            float gval = (j < 300) ? ghr[j] * wchv
                                   : gvr[j - 300] * wftl[bt * 300 + (j - 300)];
            const float* wr = wsl + j * NC;
#pragma unroll
            for (int c = 0; c < NC; c++) acc[c] = fmaf(gval, wr[c], acc[c]);
        }
    }
#pragma unroll
    for (int off = 16; off > 0; off >>= 1)
#pragma unroll
        for (int c = 0; c < NC; c++) acc[c] += __shfl_down(acc[c], off, 32);
    if (ln == 0) {
        float lg[NC];
        float mx = -1e30f;
#pragma unroll
        for (int c = 0; c < NC; c++) { lg[c] = acc[c] + bcls[c]; mx = fmaxf(mx, lg[c]); }
        float den = 0.f;
#pragma unroll
        for (int c = 0; c < NC; c++) den += expf(lg[c] - mx);
        float lden = logf(den) + mx;
#pragma unroll
        for (int c = 0; c < NC; c++) out[b * NC + c] = lg[c] - lden;
    }
}

extern "C" void kernel_launch(void* const* d_in, const int* in_sizes, int n_in,
                              void* d_out, int out_size, void* d_ws, size_t ws_size,
                              hipStream_t stream) {
    const float* x    = (const float*)d_in[0];
    const float* adj  = (const float*)d_in[1];
    const float* Wc1  = (const float*)d_in[2];
    const float* bc1  = (const float*)d_in[3];
    const float* Wc2  = (const float*)d_in[4];
    const float* bc2  = (const float*)d_in[5];
    const float* Wt   = (const float*)d_in[6];
    const float* bt   = (const float*)d_in[7];
    const float* Wa   = (const float*)d_in[8];
    const float* Wm1  = (const float*)d_in[9];
    const float* Wm2  = (const float*)d_in[10];
    const float* Wm3  = (const float*)d_in[11];
    const float* Wg1  = (const float*)d_in[12];
    const float* Wg2  = (const float*)d_in[13];
    const float* wg   = (const float*)d_in[14];
    const float* Wp1  = (const float*)d_in[15];
    const float* Wp2  = (const float*)d_in[16];
    const float* Wp3  = (const float*)d_in[17];
    const float* Wl   = (const float*)d_in[18];
    const float* Wgl  = (const float*)d_in[19];
    const float* Ws1  = (const float*)d_in[20];
    const float* Ws2  = (const float*)d_in[21];
    const float* Wf1  = (const float*)d_in[22];
    const float* Wf2  = (const float*)d_in[23];
    const float* Wcls = (const float*)d_in[24];
    const float* bcls = (const float*)d_in[25];

    float* ws  = (float*)d_ws;
    float* H2  = ws + OFS_H2;
    float* F2  = ws + OFS_F2;
    float* X1  = ws + OFS_X1;
    float* X2  = ws + OFS_X2;
    float* X3  = ws + OFS_X3;
    float* XS  = ws + OFS_XS;
    float* AF  = ws + OFS_AF;
    float* GV  = ws + OFS_GV;
    float* GH  = ws + OFS_GH;
    float* Gg  = ws + OFS_G;
    float* WCH = ws + OFS_WCH;
    float* WFT = ws + OFS_WFT;
    float* out = (float*)d_out;

    k_conv<<<dim3(8, BB), 128, 0, stream>>>(x, Wc1, bc1, Wc2, bc2, H2);
    k_f2<<<BB, 256, 0, stream>>>(H2, Wt, bt, F2);
    k_af<<<BB, 256, 0, stream>>>(F2, Wa, AF);
    k_gc<<<BB, 256, 0, stream>>>(F2, AF, Wm1, X1);
    k_gc<<<BB, 256, 0, stream>>>(X1, AF, Wm2, X2);
    k_gc<<<BB, 256, 0, stream>>>(X2, AF, Wm3, X3);
    k_xs<<<BB, 256, 0, stream>>>(F2, adj, Wg1, Wg2, XS);
    k_hg<<<BB, 256, 0, stream>>>(X1, X2, X3, XS, wg, Gg);
    k_gh<<<BB, 256, 0, stream>>>(X1, X2, X3, Gg, adj, Wp1, Wp2, Wp3, GH);  // consumes X1..X3
    k_loc<<<BB, 256, 0, stream>>>(F2, adj, Wl, GV);   // GV overlays X1/X2 (now dead)
    k_glb<<<BB, 256, 0, stream>>>(F2, AF, Wgl, GV);
    k_se<<<BB, 256, 0, stream>>>(GV, GH, Ws1, Ws2, Wf1, Wf2, WCH, WFT);
    k_cls<<<BB / 8, 256, 0, stream>>>(GH, GV, WCH, WFT, Wcls, bcls, out);
}